// Round 5
// baseline (974.655 us; speedup 1.0000x reference)
//
#include <hip/hip_runtime.h>

// ensembleThreeModel: 3-way majority-vote ensemble over softmax outputs.
// B = 65536 rows, C = 1000 classes, fp32.
// ONE WAVE (64 lanes) PER ROW: each lane owns 4 float4 chunks (j*64+lane),
// so 12 independent global loads are in flight per thread, with no LDS and
// no __syncthreads. Argmax via packed u64 (value bits || ~index) butterfly
// reduce across the wave; outputs computed from the registers already held.

#define NUM_C 1000
#define C4    250          // float4 chunks per row
#define RPB   4            // rows per block = waves per block

// Pack (value, index) so u64 max == argmax with first-occurrence tie-break.
// Softmax probs are > 0, so raw float bits are order-isomorphic; a packed
// key from a real element always beats the pk(0, idx>=1000) filler keys.
__device__ __forceinline__ unsigned long long pk(float v, int idx) {
    return ((unsigned long long)__float_as_uint(v) << 32) | (unsigned int)(~idx);
}
__device__ __forceinline__ unsigned long long pmax(unsigned long long a,
                                                   unsigned long long b) {
    return a > b ? a : b;
}

__global__ __launch_bounds__(256) void ensemble3_kernel(
    const float* __restrict__ o1, const float* __restrict__ o2,
    const float* __restrict__ o3,
    float* __restrict__ acp,          // avg_correct_prob [B,C]
    float* __restrict__ avg,          // avg_prob         [B,C]
    float* __restrict__ pred_f,       // preds as f32 (layout A) or null
    long long* __restrict__ pred_i,   // preds as i64 (layout B) or null
    int nrows)
{
    const int wave = threadIdx.x >> 6;
    const int lane = threadIdx.x & 63;
    const int row  = blockIdx.x * RPB + wave;
    if (row >= nrows) return;
    const long long base = (long long)row * NUM_C;

    const float4 z4 = make_float4(0.f, 0.f, 0.f, 0.f);
    float4 v1[4], v2[4], v3[4];

    // 12 independent loads issued up front (compiler predicates the tail).
    #pragma unroll
    for (int j = 0; j < 4; ++j) {
        const int c4 = j * 64 + lane;
        if (c4 < C4) {
            const long long off = base + 4LL * c4;
            v1[j] = *(const float4*)(o1 + off);
            v2[j] = *(const float4*)(o2 + off);
            v3[j] = *(const float4*)(o3 + off);
        } else {
            v1[j] = z4; v2[j] = z4; v3[j] = z4;   // filler keys can never win
        }
    }

    // Per-lane argmax keys over the 16 owned elements of each model.
    unsigned long long k1 = 0ull, k2 = 0ull, k3 = 0ull;
    #pragma unroll
    for (int j = 0; j < 4; ++j) {
        const int i0 = (j * 64 + lane) * 4;
        k1 = pmax(k1, pmax(pmax(pk(v1[j].x, i0),     pk(v1[j].y, i0 + 1)),
                           pmax(pk(v1[j].z, i0 + 2), pk(v1[j].w, i0 + 3))));
        k2 = pmax(k2, pmax(pmax(pk(v2[j].x, i0),     pk(v2[j].y, i0 + 1)),
                           pmax(pk(v2[j].z, i0 + 2), pk(v2[j].w, i0 + 3))));
        k3 = pmax(k3, pmax(pmax(pk(v3[j].x, i0),     pk(v3[j].y, i0 + 1)),
                           pmax(pk(v3[j].z, i0 + 2), pk(v3[j].w, i0 + 3))));
    }

    // Wave64 butterfly (6 steps); no LDS, no barrier.
    #pragma unroll
    for (int off = 32; off > 0; off >>= 1) {
        k1 = pmax(k1, __shfl_xor(k1, off));
        k2 = pmax(k2, __shfl_xor(k2, off));
        k3 = pmax(k3, __shfl_xor(k3, off));
    }
    const int pred1 = (int)(~(unsigned int)k1);
    const int pred2 = (int)(~(unsigned int)k2);
    const int pred3 = (int)(~(unsigned int)k3);

    // Majority vote, mirroring the reference's where-chain.
    const bool eq12 = pred1 == pred2;
    const bool eq13 = pred1 == pred3;
    const bool eq23 = pred2 == pred3;
    const int cmax  = (eq12 && eq13) ? 3 : ((eq12 || eq13 || eq23) ? 2 : 1);
    const int maj   = (eq12 || eq13) ? pred1 : (eq23 ? pred2 : pred1);
    const int value = (cmax < 2) ? pred3 : maj;

    if (lane == 0) {
        if (pred_i) pred_i[row] = (long long)value;
        else        pred_f[row] = (float)value;
    }

    const float m1 = (pred1 == value) ? 1.0f : 0.0f;
    const float m2 = (pred2 == value) ? 1.0f : 0.0f;
    const float m3 = (pred3 == value) ? 1.0f : 0.0f;
    const float denom = (float)cmax;

    #pragma unroll
    for (int j = 0; j < 4; ++j) {
        const int c4 = j * 64 + lane;
        if (c4 < C4) {
            float4 a, g;
            a.x = (v1[j].x * m1 + v2[j].x * m2 + v3[j].x * m3) / denom;
            a.y = (v1[j].y * m1 + v2[j].y * m2 + v3[j].y * m3) / denom;
            a.z = (v1[j].z * m1 + v2[j].z * m2 + v3[j].z * m3) / denom;
            a.w = (v1[j].w * m1 + v2[j].w * m2 + v3[j].w * m3) / denom;
            g.x = (v1[j].x + v2[j].x + v3[j].x) / 3.0f;
            g.y = (v1[j].y + v2[j].y + v3[j].y) / 3.0f;
            g.z = (v1[j].z + v2[j].z + v3[j].z) / 3.0f;
            g.w = (v1[j].w + v2[j].w + v3[j].w) / 3.0f;
            const long long off = base + 4LL * c4;
            *(float4*)(acp + off) = a;
            *(float4*)(avg + off) = g;
        }
    }
}

extern "C" void kernel_launch(void* const* d_in, const int* in_sizes, int n_in,
                              void* d_out, int out_size, void* d_ws, size_t ws_size,
                              hipStream_t stream) {
    const float* o1 = (const float*)d_in[0];
    const float* o2 = (const float*)d_in[1];
    const float* o3 = (const float*)d_in[2];

    const long long BC = in_sizes[0];        // B * C
    const long long B  = BC / NUM_C;

    float* outf = (float*)d_out;
    float*     pred_f = nullptr;
    long long* pred_i = nullptr;
    float*     acp;

    if ((long long)out_size == 2LL * B + 2LL * BC) {
        // Layout B: preds kept as raw int64 (occupy 2*B float slots).
        pred_i = (long long*)d_out;
        acp = outf + 2LL * B;
    } else {
        // Layout A (default): preds converted to the common float dtype.
        pred_f = outf;
        acp = outf + B;
    }
    float* avg = acp + BC;

    const int nblocks = (int)((B + RPB - 1) / RPB);
    ensemble3_kernel<<<dim3(nblocks), dim3(256), 0, stream>>>(
        o1, o2, o3, acp, avg, pred_f, pred_i, (int)B);
}